// Round 1
// baseline (8475.700 us; speedup 1.0000x reference)
//
#include <hip/hip_runtime.h>
#include <math.h>

// ---------------- problem constants ----------------
#define T_IN  16
#define T1    14
#define T2    12
#define NB    16
#define NPROP 4096
#define NDEV  1024
#define NROOM 256
#define NR    4096    // B*N_ROOM
#define ND    16384   // B*N_DEV
#define NP    65536   // B*N_PROP
// B*N_OUT = B*N_TIME = 16

// ---------------- workspace layout (floats) ----------------
constexpr size_t SZ_PF = (size_t)T1 * NP * 64;   // 58,720,256
constexpr size_t SZ_DF = (size_t)T1 * ND * 64;   // 14,680,064
constexpr size_t SZ_RF = (size_t)T1 * NR * 64;   //  3,670,016
constexpr size_t SZ_OF = (size_t)T1 * 16 * 64;   //     14,336

constexpr size_t O_PF   = 0;
constexpr size_t O_DF   = O_PF + SZ_PF;
constexpr size_t O_RF   = O_DF + SZ_DF;
constexpr size_t O_H0   = O_RF + SZ_RF;
constexpr size_t O_H1   = O_H0 + SZ_RF;
constexpr size_t O_OF   = O_H1 + SZ_RF;
constexpr size_t O_TF   = O_OF + SZ_OF;
constexpr size_t O_WSR  = O_TF + SZ_OF;      // Wr0+Wr2+Wr3 (4096)
constexpr size_t O_WSD  = O_WSR + 4096;      // Wr1+Wr4     (4096)
constexpr size_t O_BSR  = O_WSD + 4096;      // summed room bias (64)
constexpr size_t O_BSD  = O_BSR + 64;        // summed dev bias  (64)
constexpr size_t O_DINV0= O_BSD + 64;
constexpr size_t O_DINV1= O_DINV0 + 4096;
constexpr size_t O_RCDR = O_DINV1 + 4096;
constexpr size_t O_RCOR = O_RCDR + 4096;
constexpr size_t O_RCTR = O_RCOR + 4096;
constexpr size_t O_RCPD = O_RCTR + 4096;
constexpr size_t O_RCTD = O_RCPD + 16384;
constexpr size_t O_RCTP = O_RCTD + 16384;
// ---- zero-initialized region starts here ----
constexpr size_t O_ZERO  = O_RCTP + 65536;
constexpr size_t O_ROOMG = O_ZERO;                    // gcn edge scatter acc / room_s (3,670,016)
constexpr size_t O_AGGDR = O_ROOMG + SZ_RF;           // sage dr agg                   (3,670,016)
constexpr size_t O_AGGPD = O_AGGDR + SZ_RF;           // sage pd agg / dev_s          (14,680,064)
constexpr size_t O_DEG0  = O_AGGPD + SZ_DF;
constexpr size_t O_DEG1  = O_DEG0 + 4096;
constexpr size_t O_CNTDR = O_DEG1 + 4096;
constexpr size_t O_CNTPD = O_CNTDR + 4096;
constexpr size_t O_MOR   = O_CNTPD + 16384;           // 4096 x 16
constexpr size_t O_MTR   = O_MOR + 65536;             // 4096 x 16
constexpr size_t O_MTD   = O_MTR + 65536;             // 16384 x 16
constexpr size_t O_MTP   = O_MTD + 262144;            // 65536 x 16
constexpr size_t O_END   = O_MTP + 1048576;
constexpr size_t ZERO_CNT = O_END - O_ZERO;           // 23,490,560 floats

// output (floats) offsets in d_out (NCHW, concatenated in return order)
constexpr size_t OUT_ROOM = 0;
constexpr size_t OUT_DEV  = 3145728;
constexpr size_t OUT_PROP = 15728640;
constexpr size_t OUT_OUT  = 66060288;
constexpr size_t OUT_TIME = 66072576;

__device__ __forceinline__ float sigm(float x) { return 1.f / (1.f + __expf(-x)); }

// 64x64 matmul accumulate: acc[d] += sum_c x[c] * W[c*64+d]
__device__ __forceinline__ void mm64(float4 acc[16], const float x[64], const float* __restrict__ W) {
#pragma unroll
  for (int c = 0; c < 64; ++c) {
    const float a = x[c];
    const float4* Wr = (const float4*)(W + c * 64);
#pragma unroll
    for (int d = 0; d < 16; ++d) {
      const float4 w = Wr[d];
      acc[d].x += a * w.x; acc[d].y += a * w.y; acc[d].z += a * w.z; acc[d].w += a * w.w;
    }
  }
}

// ---------------- small prep kernels ----------------
__global__ void k_prep(const float* __restrict__ sWr, const float* __restrict__ gcnb,
                       const float* __restrict__ sbl, float* __restrict__ Wsr,
                       float* __restrict__ Wsd, float* __restrict__ bsr, float* __restrict__ bsd) {
  const int k = blockIdx.x * 256 + threadIdx.x;
  if (k < 4096) {
    Wsr[k] = sWr[k] + sWr[2 * 4096 + k] + sWr[3 * 4096 + k];
    Wsd[k] = sWr[4096 + k] + sWr[4 * 4096 + k];
  }
  if (k < 64) {
    bsr[k] = gcnb[k] + gcnb[64 + k] + sbl[k] + sbl[2 * 64 + k] + sbl[3 * 64 + k];
    bsd[k] = sbl[64 + k] + sbl[4 * 64 + k];
  }
}

__global__ void k_count_w(const int* __restrict__ dst, const float* __restrict__ w, int E,
                          float* __restrict__ deg) {
  const int e = blockIdx.x * 256 + threadIdx.x;
  if (e < E) atomicAdd(&deg[dst[e]], w[e]);
}
__global__ void k_count1(const int* __restrict__ dst, int E, float* __restrict__ cnt) {
  const int e = blockIdx.x * 256 + threadIdx.x;
  if (e < E) atomicAdd(&cnt[dst[e]], 1.f);
}
__global__ void k_cmat(const int* __restrict__ src, const int* __restrict__ dst, int E,
                       float* __restrict__ M) {
  const int e = blockIdx.x * 256 + threadIdx.x;
  if (e < E) atomicAdd(&M[(size_t)dst[e] * 16 + src[e]], 1.f);
}

__global__ void k_finalize(const float* __restrict__ deg0, const float* __restrict__ deg1,
                           const float* __restrict__ cntdr, const float* __restrict__ cntpd,
                           const float* __restrict__ MOR, const float* __restrict__ MTR,
                           const float* __restrict__ MTD, const float* __restrict__ MTP,
                           float* __restrict__ dinv0, float* __restrict__ dinv1,
                           float* __restrict__ rcdr, float* __restrict__ rcor,
                           float* __restrict__ rctr, float* __restrict__ rcpd,
                           float* __restrict__ rctd, float* __restrict__ rctp) {
  const int i = blockIdx.x * 256 + threadIdx.x;  // 65536 threads
  if (i < 4096) {
    dinv0[i] = rsqrtf(deg0[i] + 1.f);   // +1 = self-loop weight
    dinv1[i] = rsqrtf(deg1[i] + 1.f);
    rcdr[i] = 1.f / fmaxf(cntdr[i], 1.f);
    float s0 = 0.f, s1 = 0.f;
    for (int s = 0; s < 16; ++s) { s0 += MOR[i * 16 + s]; s1 += MTR[i * 16 + s]; }
    rcor[i] = 1.f / fmaxf(s0, 1.f);
    rctr[i] = 1.f / fmaxf(s1, 1.f);
  }
  if (i < 16384) {
    rcpd[i] = 1.f / fmaxf(cntpd[i], 1.f);
    float s = 0.f;
    for (int k = 0; k < 16; ++k) s += MTD[i * 16 + k];
    rctd[i] = 1.f / fmaxf(s, 1.f);
  }
  {
    float s = 0.f;
    for (int k = 0; k < 16; ++k) s += MTP[(size_t)i * 16 + k];
    rctp[i] = 1.f / fmaxf(s, 1.f);
  }
}

// ---------------- NCHW (T sliced to T1) -> flat (T, B*N, C) ----------------
__global__ __launch_bounds__(256) void k_transpose(const float* __restrict__ x,
                                                   float* __restrict__ xf, int N) {
  __shared__ float tile[64][65];
  const int lane = threadIdx.x & 63, wave = threadIdx.x >> 6;
  const int n0 = blockIdx.x * 64, t = blockIdx.y, b = blockIdx.z;
#pragma unroll
  for (int cc = wave; cc < 64; cc += 4)
    tile[cc][lane] = x[(((size_t)b * 64 + cc) * T_IN + t) * N + n0 + lane];
  __syncthreads();
  const size_t NN = (size_t)NB * N;
#pragma unroll
  for (int nn = wave; nn < 64; nn += 4)
    xf[((size_t)t * NN + (size_t)b * N + n0 + nn) * 64 + lane] = tile[lane][nn];
}

// ---------------- GLU conv1 on property: NCHW in -> flat pf out ----------------
__global__ __launch_bounds__(256) void k_glu_conv1_prop(const float* __restrict__ x,
                                                        const float* __restrict__ W,
                                                        const float* __restrict__ bias,
                                                        float* __restrict__ pf) {
  __shared__ float xs[192 * 65];
  const int lane = threadIdx.x & 63, wave = threadIdx.x >> 6;
  const int n0 = blockIdx.x * 64, t = blockIdx.y, b = blockIdx.z;
  for (int r = wave; r < 192; r += 4) {
    const int i = r / 3, k = r - i * 3;
    xs[r * 65 + lane] = x[(((size_t)b * 64 + i) * T_IN + (t + k)) * NPROP + n0 + lane];
  }
  __syncthreads();
  const int c0 = wave * 16;
  float accp[16], accq[16];
#pragma unroll
  for (int j = 0; j < 16; ++j) { accp[j] = 0.f; accq[j] = 0.f; }
  for (int r0 = 0; r0 < 192; r0 += 4) {
    const float x0 = xs[(r0 + 0) * 65 + lane];
    const float x1 = xs[(r0 + 1) * 65 + lane];
    const float x2 = xs[(r0 + 2) * 65 + lane];
    const float x3 = xs[(r0 + 3) * 65 + lane];
#pragma unroll
    for (int j = 0; j < 16; ++j) {
      const float4 wp = *(const float4*)(W + (size_t)(c0 + j) * 192 + r0);
      accp[j] += wp.x * x0 + wp.y * x1 + wp.z * x2 + wp.w * x3;
      const float4 wq = *(const float4*)(W + (size_t)(c0 + j + 64) * 192 + r0);
      accq[j] += wq.x * x0 + wq.y * x1 + wq.z * x2 + wq.w * x3;
    }
  }
  const size_t base = ((size_t)t * NP + (size_t)b * NPROP + n0 + lane) * 64;
#pragma unroll
  for (int j4 = 0; j4 < 4; ++j4) {
    float4 o;
    float* po = (float*)&o;
#pragma unroll
    for (int jj = 0; jj < 4; ++jj) {
      const int j = j4 * 4 + jj;
      const int c = c0 + j;
      const float P = accp[j] + bias[c];
      const float Q = accq[j] + bias[c + 64];
      const float xin = xs[(c * 3 + 2) * 65 + lane];
      po[jj] = (P + xin) * sigm(Q);
    }
    *(float4*)(pf + base + c0 + j4 * 4) = o;
  }
}

// ---------------- GLU conv2 on prop: flat in (relu on read) -> fused LN -> NCHW out ----------------
__global__ __launch_bounds__(256) void k_glu_conv2_prop(const float* __restrict__ xf,
                                                        const float* __restrict__ W,
                                                        const float* __restrict__ bias,
                                                        const float* __restrict__ lg,
                                                        const float* __restrict__ lb,
                                                        float* __restrict__ out) {
  __shared__ float xs[192 * 65];
  __shared__ float red1[4][64];
  __shared__ float red2[4][64];
  const int lane = threadIdx.x & 63, wave = threadIdx.x >> 6;
  const int n0 = blockIdx.x * 64, t = blockIdx.y, b = blockIdx.z;
  const int i4 = (lane & 15) * 4;
  for (int p = wave; p < 48; p += 4) {
    const int k = p >> 4;
    const int n = (p & 15) * 4 + (lane >> 4);
    const float4 v =
        *(const float4*)(xf + ((size_t)(t + k) * NP + (size_t)b * NPROP + n0 + n) * 64 + i4);
    xs[((i4 + 0) * 3 + k) * 65 + n] = fmaxf(v.x, 0.f);
    xs[((i4 + 1) * 3 + k) * 65 + n] = fmaxf(v.y, 0.f);
    xs[((i4 + 2) * 3 + k) * 65 + n] = fmaxf(v.z, 0.f);
    xs[((i4 + 3) * 3 + k) * 65 + n] = fmaxf(v.w, 0.f);
  }
  __syncthreads();
  const int c0 = wave * 16;
  float accp[16], accq[16];
#pragma unroll
  for (int j = 0; j < 16; ++j) { accp[j] = 0.f; accq[j] = 0.f; }
  for (int r0 = 0; r0 < 192; r0 += 4) {
    const float x0 = xs[(r0 + 0) * 65 + lane];
    const float x1 = xs[(r0 + 1) * 65 + lane];
    const float x2 = xs[(r0 + 2) * 65 + lane];
    const float x3 = xs[(r0 + 3) * 65 + lane];
#pragma unroll
    for (int j = 0; j < 16; ++j) {
      const float4 wp = *(const float4*)(W + (size_t)(c0 + j) * 192 + r0);
      accp[j] += wp.x * x0 + wp.y * x1 + wp.z * x2 + wp.w * x3;
      const float4 wq = *(const float4*)(W + (size_t)(c0 + j + 64) * 192 + r0);
      accq[j] += wq.x * x0 + wq.y * x1 + wq.z * x2 + wq.w * x3;
    }
  }
  float o[16];
  float s1 = 0.f, s2 = 0.f;
#pragma unroll
  for (int j = 0; j < 16; ++j) {
    const int c = c0 + j;
    const float P = accp[j] + bias[c];
    const float Q = accq[j] + bias[c + 64];
    const float xin = xs[(c * 3 + 2) * 65 + lane];  // already relu'd
    o[j] = (P + xin) * sigm(Q);
    s1 += o[j];
    s2 += o[j] * o[j];
  }
  red1[wave][lane] = s1;
  red2[wave][lane] = s2;
  __syncthreads();
  const float t1 = red1[0][lane] + red1[1][lane] + red1[2][lane] + red1[3][lane];
  const float t2 = red2[0][lane] + red2[1][lane] + red2[2][lane] + red2[3][lane];
  const float m = t1 * (1.f / 64.f);
  const float var = t2 * (1.f / 64.f) - m * m;
  const float rs = rsqrtf(var + 1e-5f);
#pragma unroll
  for (int j = 0; j < 16; ++j) {
    const int c = c0 + j;
    out[(((size_t)b * 64 + c) * T2 + t) * NPROP + n0 + lane] = (o[j] - m) * rs * lg[c] + lb[c];
  }
}

// ---------------- GLU conv, N==1 tensors ----------------
// conv1 variant: NCHW in (T_IN), flat out (pre-relu)
__global__ __launch_bounds__(64) void k_glu_conv_small1(const float* __restrict__ x,
                                                        const float* __restrict__ W,
                                                        const float* __restrict__ bias,
                                                        float* __restrict__ xfout) {
  __shared__ float xl[192];
  const int c = threadIdx.x;
  const int t = blockIdx.x, b = blockIdx.y;
  for (int r = c; r < 192; r += 64) {
    const int i = r / 3, k = r - (r / 3) * 3;
    xl[r] = x[((size_t)b * 64 + i) * T_IN + (t + k)];
  }
  __syncthreads();
  float p = 0.f, q = 0.f;
  for (int r0 = 0; r0 < 192; r0 += 4) {
    const float4 xv = *(const float4*)(xl + r0);
    const float4 wp = *(const float4*)(W + (size_t)c * 192 + r0);
    const float4 wq = *(const float4*)(W + (size_t)(c + 64) * 192 + r0);
    p += wp.x * xv.x + wp.y * xv.y + wp.z * xv.z + wp.w * xv.w;
    q += wq.x * xv.x + wq.y * xv.y + wq.z * xv.z + wq.w * xv.w;
  }
  const float xin = xl[c * 3 + 2];
  xfout[((size_t)t * 16 + b) * 64 + c] = (p + bias[c] + xin) * sigm(q + bias[c + 64]);
}

// conv2 variant: flat in (relu on read, T1 rows), fused LN, NCHW out (N==1)
__global__ __launch_bounds__(64) void k_glu_conv_small2(const float* __restrict__ xfin,
                                                        const float* __restrict__ W,
                                                        const float* __restrict__ bias,
                                                        const float* __restrict__ lg,
                                                        const float* __restrict__ lb,
                                                        float* __restrict__ out) {
  __shared__ float xl[192];
  const int c = threadIdx.x;
  const int t = blockIdx.x, b = blockIdx.y;
  for (int r = c; r < 192; r += 64) {
    const int i = r / 3, k = r - (r / 3) * 3;
    xl[r] = fmaxf(xfin[((size_t)(t + k) * 16 + b) * 64 + i], 0.f);
  }
  __syncthreads();
  float p = 0.f, q = 0.f;
  for (int r0 = 0; r0 < 192; r0 += 4) {
    const float4 xv = *(const float4*)(xl + r0);
    const float4 wp = *(const float4*)(W + (size_t)c * 192 + r0);
    const float4 wq = *(const float4*)(W + (size_t)(c + 64) * 192 + r0);
    p += wp.x * xv.x + wp.y * xv.y + wp.z * xv.z + wp.w * xv.w;
    q += wq.x * xv.x + wq.y * xv.y + wq.z * xv.z + wq.w * xv.w;
  }
  const float xin = xl[c * 3 + 2];
  const float o = (p + bias[c] + xin) * sigm(q + bias[c + 64]);
  float s1 = o, s2 = o * o;
#pragma unroll
  for (int off = 32; off > 0; off >>= 1) {
    s1 += __shfl_xor(s1, off);
    s2 += __shfl_xor(s2, off);
  }
  const float m = s1 * (1.f / 64.f);
  const float var = s2 * (1.f / 64.f) - m * m;
  out[((size_t)b * 64 + c) * T2 + t] = (o - m) * rsqrtf(var + 1e-5f) * lg[c] + lb[c];
}

// ---------------- h = rf @ gcn_W[g], g in {0,1} ----------------
__global__ __launch_bounds__(256) void k_gcn_h(const float* __restrict__ rf,
                                               const float* __restrict__ gcnW,
                                               float* __restrict__ h0, float* __restrict__ h1) {
  const int idx = blockIdx.x * 256 + threadIdx.x;
  const int i = idx & 4095;
  const int tg = idx >> 12;
  const int t = tg % 14;
  const int g = tg / 14;
  if (g >= 2) return;
  const size_t row = ((size_t)t * NR + i) * 64;
  float x[64];
  const float4* xr = (const float4*)(rf + row);
#pragma unroll
  for (int c4 = 0; c4 < 16; ++c4) {
    const float4 v = xr[c4];
    x[c4 * 4] = v.x; x[c4 * 4 + 1] = v.y; x[c4 * 4 + 2] = v.z; x[c4 * 4 + 3] = v.w;
  }
  float4 acc[16];
#pragma unroll
  for (int d = 0; d < 16; ++d) acc[d] = make_float4(0.f, 0.f, 0.f, 0.f);
  mm64(acc, x, gcnW + (size_t)g * 4096);
  float4* po = (float4*)((g ? h1 : h0) + row);
#pragma unroll
  for (int d = 0; d < 16; ++d) po[d] = acc[d];
}

// ---------------- edge scatters (atomics) ----------------
__global__ __launch_bounds__(256) void k_scatter_gcn(const int* __restrict__ src,
                                                     const int* __restrict__ dst,
                                                     const float* __restrict__ w, int E,
                                                     const float* __restrict__ h,
                                                     const float* __restrict__ dinv,
                                                     float* __restrict__ outacc) {
  const int gid = blockIdx.x * 256 + threadIdx.x;
  if (gid >= E * 224) return;
  const int cq = gid & 15;
  const int t = (gid >> 4) % 14;
  const int e = gid / 224;
  const int s = src[e], d = dst[e];
  const float nrm = dinv[s] * w[e] * dinv[d];
  const float4 hv = *(const float4*)(h + ((size_t)t * NR + s) * 64 + cq * 4);
  float* o = outacc + ((size_t)t * NR + d) * 64 + cq * 4;
  atomicAdd(o + 0, hv.x * nrm);
  atomicAdd(o + 1, hv.y * nrm);
  atomicAdd(o + 2, hv.z * nrm);
  atomicAdd(o + 3, hv.w * nrm);
}

__global__ __launch_bounds__(256) void k_scatter_sage(const int* __restrict__ src,
                                                      const int* __restrict__ dst, int E,
                                                      const float* __restrict__ xsrc, int NNsrc,
                                                      float* __restrict__ agg, int NNdst) {
  const int gid = blockIdx.x * 256 + threadIdx.x;
  if (gid >= E * 224) return;
  const int cq = gid & 15;
  const int t = (gid >> 4) % 14;
  const int e = gid / 224;
  const int s = src[e], d = dst[e];
  const float4 v = *(const float4*)(xsrc + ((size_t)t * NNsrc + s) * 64 + cq * 4);
  float* o = agg + ((size_t)t * NNdst + d) * 64 + cq * 4;
  atomicAdd(o + 0, v.x);
  atomicAdd(o + 1, v.y);
  atomicAdd(o + 2, v.z);
  atomicAdd(o + 3, v.w);
}

// ---------------- node "final" kernels ----------------
__global__ __launch_bounds__(256) void k_room_final(
    const float* __restrict__ rf, const float* __restrict__ h0, const float* __restrict__ h1,
    const float* __restrict__ aggdr, const float* __restrict__ of, const float* __restrict__ tf,
    const float* __restrict__ MOR, const float* __restrict__ MTR, const float* __restrict__ dinv0,
    const float* __restrict__ dinv1, const float* __restrict__ rcdr,
    const float* __restrict__ rcor, const float* __restrict__ rctr, const float* __restrict__ Wl,
    const float* __restrict__ Wsr, const float* __restrict__ bsr, float* __restrict__ roomg) {
  const int idx = blockIdx.x * 256 + threadIdx.x;
  const int i = idx & 4095;
  const int t = idx >> 12;
  if (t >= 14) return;
  const size_t row = ((size_t)t * NR + i) * 64;
  const float d0 = dinv0[i], d1 = dinv1[i];
  const float d0sq = d0 * d0, d1sq = d1 * d1;
  float4 acc[16];
  {
    const float4* pg = (const float4*)(roomg + row);
    const float4* p0 = (const float4*)(h0 + row);
    const float4* p1 = (const float4*)(h1 + row);
    const float4* pb = (const float4*)bsr;
#pragma unroll
    for (int d = 0; d < 16; ++d) {
      float4 a = pg[d];
      const float4 v0 = p0[d], v1 = p1[d], bb = pb[d];
      a.x += bb.x + v0.x * d0sq + v1.x * d1sq;
      a.y += bb.y + v0.y * d0sq + v1.y * d1sq;
      a.z += bb.z + v0.z * d0sq + v1.z * d1sq;
      a.w += bb.w + v0.w * d0sq + v1.w * d1sq;
      acc[d] = a;
    }
  }
  float x[64];
  // SAGE dr (dev -> room)
  {
    const float rc = rcdr[i];
    const float4* pa = (const float4*)(aggdr + row);
#pragma unroll
    for (int c4 = 0; c4 < 16; ++c4) {
      const float4 v = pa[c4];
      x[c4 * 4] = v.x * rc; x[c4 * 4 + 1] = v.y * rc; x[c4 * 4 + 2] = v.z * rc; x[c4 * 4 + 3] = v.w * rc;
    }
  }
  mm64(acc, x, Wl);  // Wl0
  // SAGE or (outside -> room) via count matrix
  {
#pragma unroll
    for (int c = 0; c < 64; ++c) x[c] = 0.f;
    for (int s = 0; s < 16; ++s) {
      const float ms = MOR[i * 16 + s];
      const float4* pr = (const float4*)(of + ((size_t)t * 16 + s) * 64);
#pragma unroll
      for (int c4 = 0; c4 < 16; ++c4) {
        const float4 v = pr[c4];
        x[c4 * 4] += ms * v.x; x[c4 * 4 + 1] += ms * v.y; x[c4 * 4 + 2] += ms * v.z; x[c4 * 4 + 3] += ms * v.w;
      }
    }
    const float rc = rcor[i];
#pragma unroll
    for (int c = 0; c < 64; ++c) x[c] *= rc;
  }
  mm64(acc, x, Wl + 2 * 4096);  // Wl2
  // SAGE tr (time -> room) via count matrix
  {
#pragma unroll
    for (int c = 0; c < 64; ++c) x[c] = 0.f;
    for (int s = 0; s < 16; ++s) {
      const float ms = MTR[i * 16 + s];
      const float4* pr = (const float4*)(tf + ((size_t)t * 16 + s) * 64);
#pragma unroll
      for (int c4 = 0; c4 < 16; ++c4) {
        const float4 v = pr[c4];
        x[c4 * 4] += ms * v.x; x[c4 * 4 + 1] += ms * v.y; x[c4 * 4 + 2] += ms * v.z; x[c4 * 4 + 3] += ms * v.w;
      }
    }
    const float rc = rctr[i];
#pragma unroll
    for (int c = 0; c < 64; ++c) x[c] *= rc;
  }
  mm64(acc, x, Wl + 3 * 4096);  // Wl3
  // rf @ (Wr0+Wr2+Wr3)
  {
    const float4* pr = (const float4*)(rf + row);
#pragma unroll
    for (int c4 = 0; c4 < 16; ++c4) {
      const float4 v = pr[c4];
      x[c4 * 4] = v.x; x[c4 * 4 + 1] = v.y; x[c4 * 4 + 2] = v.z; x[c4 * 4 + 3] = v.w;
    }
  }
  mm64(acc, x, Wsr);
  float4* po = (float4*)(roomg + row);
#pragma unroll
  for (int d = 0; d < 16; ++d) po[d] = acc[d];
}

__global__ __launch_bounds__(256) void k_dev_final(float* __restrict__ aggpd,
                                                   const float* __restrict__ df,
                                                   const float* __restrict__ tf,
                                                   const float* __restrict__ MTD,
                                                   const float* __restrict__ rcpd,
                                                   const float* __restrict__ rctd,
                                                   const float* __restrict__ Wl,
                                                   const float* __restrict__ Wsd,
                                                   const float* __restrict__ bsd) {
  const int idx = blockIdx.x * 256 + threadIdx.x;
  const int i = idx & 16383;
  const int t = idx >> 14;
  if (t >= 14) return;
  const size_t row = ((size_t)t * ND + i) * 64;
  float4 acc[16];
  const float4* pb = (const float4*)bsd;
#pragma unroll
  for (int d = 0; d < 16; ++d) acc[d] = pb[d];
  float x[64];
  // SAGE pd (prop -> dev)
  {
    const float rc = rcpd[i];
    const float4* pa = (const float4*)(aggpd + row);
#pragma unroll
    for (int c4 = 0; c4 < 16; ++c4) {
      const float4 v = pa[c4];
      x[c4 * 4] = v.x * rc; x[c4 * 4 + 1] = v.y * rc; x[c4 * 4 + 2] = v.z * rc; x[c4 * 4 + 3] = v.w * rc;
    }
  }
  mm64(acc, x, Wl + 1 * 4096);  // Wl1
  // SAGE td (time -> dev)
  {
#pragma unroll
    for (int c = 0; c < 64; ++c) x[c] = 0.f;
    for (int s = 0; s < 16; ++s) {
      const float ms = MTD[(size_t)i * 16 + s];
      const float4* pr = (const float4*)(tf + ((size_t)t * 16 + s) * 64);
#pragma unroll
      for (int c4 = 0; c4 < 16; ++c4) {
        const float4 v = pr[c4];
        x[c4 * 4] += ms * v.x; x[c4 * 4 + 1] += ms * v.y; x[c4 * 4 + 2] += ms * v.z; x[c4 * 4 + 3] += ms * v.w;
      }
    }
    const float rc = rctd[i];
#pragma unroll
    for (int c = 0; c < 64; ++c) x[c] *= rc;
  }
  mm64(acc, x, Wl + 4 * 4096);  // Wl4
  // df @ (Wr1+Wr4)
  {
    const float4* pr = (const float4*)(df + row);
#pragma unroll
    for (int c4 = 0; c4 < 16; ++c4) {
      const float4 v = pr[c4];
      x[c4 * 4] = v.x; x[c4 * 4 + 1] = v.y; x[c4 * 4 + 2] = v.z; x[c4 * 4 + 3] = v.w;
    }
  }
  mm64(acc, x, Wsd);
  float4* po = (float4*)(aggpd + row);
#pragma unroll
  for (int d = 0; d < 16; ++d) po[d] = acc[d];
}

__global__ __launch_bounds__(256) void k_prop_final(float* __restrict__ pf,
                                                    const float* __restrict__ tf,
                                                    const float* __restrict__ MTP,
                                                    const float* __restrict__ rctp,
                                                    const float* __restrict__ Wl5,
                                                    const float* __restrict__ Wr5,
                                                    const float* __restrict__ bl5) {
  const int idx = blockIdx.x * 256 + threadIdx.x;
  const int i = idx & 65535;
  const int t = idx >> 16;
  if (t >= 14) return;
  const size_t row = ((size_t)t * NP + i) * 64;
  float4 acc[16];
  const float4* pb = (const float4*)bl5;
#pragma unroll
  for (int d = 0; d < 16; ++d) acc[d] = pb[d];
  float x[64];
  // SAGE tp (time -> prop)
  {
#pragma unroll
    for (int c = 0; c < 64; ++c) x[c] = 0.f;
    for (int s = 0; s < 16; ++s) {
      const float ms = MTP[(size_t)i * 16 + s];
      const float4* pr = (const float4*)(tf + ((size_t)t * 16 + s) * 64);
#pragma unroll
      for (int c4 = 0; c4 < 16; ++c4) {
        const float4 v = pr[c4];
        x[c4 * 4] += ms * v.x; x[c4 * 4 + 1] += ms * v.y; x[c4 * 4 + 2] += ms * v.z; x[c4 * 4 + 3] += ms * v.w;
      }
    }
    const float rc = rctp[i];
#pragma unroll
    for (int c = 0; c < 64; ++c) x[c] *= rc;
  }
  mm64(acc, x, Wl5);
  // pf @ Wr5
  {
    const float4* pr = (const float4*)(pf + row);
#pragma unroll
    for (int c4 = 0; c4 < 16; ++c4) {
      const float4 v = pr[c4];
      x[c4 * 4] = v.x; x[c4 * 4 + 1] = v.y; x[c4 * 4 + 2] = v.z; x[c4 * 4 + 3] = v.w;
    }
  }
  mm64(acc, x, Wr5);
  float4* po = (float4*)(pf + row);
#pragma unroll
  for (int d = 0; d < 16; ++d) po[d] = acc[d];
}

// ---------------- relu + layernorm over C + flat -> NCHW, for room/dev ----------------
template <int N>
__global__ __launch_bounds__(256) void k_ln_flat(const float* __restrict__ xf,
                                                 const float* __restrict__ lg,
                                                 const float* __restrict__ lb,
                                                 float* __restrict__ out) {
  const int idx = blockIdx.x * 256 + threadIdx.x;
  const int n = idx % N;
  const int t = (idx / N) % T2;
  const int b = idx / (N * T2);
  if (b >= NB) return;
  const float4* pr = (const float4*)(xf + ((size_t)t * (NB * N) + (size_t)b * N + n) * 64);
  float v[64];
  float s1 = 0.f, s2 = 0.f;
#pragma unroll
  for (int c4 = 0; c4 < 16; ++c4) {
    float4 a = pr[c4];
    a.x = fmaxf(a.x, 0.f); a.y = fmaxf(a.y, 0.f); a.z = fmaxf(a.z, 0.f); a.w = fmaxf(a.w, 0.f);
    v[c4 * 4] = a.x; v[c4 * 4 + 1] = a.y; v[c4 * 4 + 2] = a.z; v[c4 * 4 + 3] = a.w;
    s1 += a.x + a.y + a.z + a.w;
    s2 += a.x * a.x + a.y * a.y + a.z * a.z + a.w * a.w;
  }
  const float m = s1 * (1.f / 64.f);
  const float var = s2 * (1.f / 64.f) - m * m;
  const float rs = rsqrtf(var + 1e-5f);
#pragma unroll
  for (int c = 0; c < 64; ++c)
    out[(((size_t)b * 64 + c) * T2 + t) * N + n] = (v[c] - m) * rs * lg[c] + lb[c];
}

// ---------------- host launcher ----------------
extern "C" void kernel_launch(void* const* d_in, const int* in_sizes, int n_in, void* d_out,
                              int out_size, void* d_ws, size_t ws_size, hipStream_t stream) {
  (void)n_in; (void)out_size; (void)ws_size;
  const float* x_room = (const float*)d_in[0];
  const float* x_device = (const float*)d_in[1];
  const float* x_property = (const float*)d_in[2];
  const float* x_outside = (const float*)d_in[3];
  const float* x_time = (const float*)d_in[4];
  const float* conv1_W = (const float*)d_in[5];
  const float* conv1_b = (const float*)d_in[6];
  const float* conv2_W = (const float*)d_in[7];
  const float* conv2_b = (const float*)d_in[8];
  const float* gcn_W = (const float*)d_in[9];
  const float* gcn_b = (const float*)d_in[10];
  const float* sage_Wl = (const float*)d_in[11];
  const float* sage_bl = (const float*)d_in[12];
  const float* sage_Wr = (const float*)d_in[13];
  const float* ln_g = (const float*)d_in[14];
  const float* ln_b = (const float*)d_in[15];
  const float* hh_w = (const float*)d_in[16];
  const float* hv_w = (const float*)d_in[17];
  const int* hh_src = (const int*)d_in[18];
  const int* hh_dst = (const int*)d_in[19];
  const int* hv_src = (const int*)d_in[20];
  const int* hv_dst = (const int*)d_in[21];
  const int* dr_src = (const int*)d_in[22];
  const int* dr_dst = (const int*)d_in[23];
  const int* pd_src = (const int*)d_in[24];
  const int* pd_dst = (const int*)d_in[25];
  const int* or_src = (const int*)d_in[26];
  const int* or_dst = (const int*)d_in[27];
  const int* tr_src = (const int*)d_in[28];
  const int* tr_dst = (const int*)d_in[29];
  const int* td_src = (const int*)d_in[30];
  const int* td_dst = (const int*)d_in[31];
  const int* tp_src = (const int*)d_in[32];
  const int* tp_dst = (const int*)d_in[33];
  const int E_hh = in_sizes[18], E_hv = in_sizes[20], E_dr = in_sizes[22], E_pd = in_sizes[24];
  const int E_or = in_sizes[26], E_tr = in_sizes[28], E_td = in_sizes[30], E_tp = in_sizes[32];

  float* ws = (float*)d_ws;
  float* out = (float*)d_out;

  // zero the accumulator / counter region
  hipMemsetAsync(ws + O_ZERO, 0, ZERO_CNT * sizeof(float), stream);

  // weight/bias pre-sums
  k_prep<<<16, 256, 0, stream>>>(sage_Wr, gcn_b, sage_bl, ws + O_WSR, ws + O_WSD, ws + O_BSR,
                                 ws + O_BSD);

  // degree / count building
  k_count_w<<<(E_hh + 255) / 256, 256, 0, stream>>>(hh_dst, hh_w, E_hh, ws + O_DEG0);
  k_count_w<<<(E_hv + 255) / 256, 256, 0, stream>>>(hv_dst, hv_w, E_hv, ws + O_DEG1);
  k_count1<<<(E_dr + 255) / 256, 256, 0, stream>>>(dr_dst, E_dr, ws + O_CNTDR);
  k_count1<<<(E_pd + 255) / 256, 256, 0, stream>>>(pd_dst, E_pd, ws + O_CNTPD);
  k_cmat<<<(E_or + 255) / 256, 256, 0, stream>>>(or_src, or_dst, E_or, ws + O_MOR);
  k_cmat<<<(E_tr + 255) / 256, 256, 0, stream>>>(tr_src, tr_dst, E_tr, ws + O_MTR);
  k_cmat<<<(E_td + 255) / 256, 256, 0, stream>>>(td_src, td_dst, E_td, ws + O_MTD);
  k_cmat<<<(E_tp + 255) / 256, 256, 0, stream>>>(tp_src, tp_dst, E_tp, ws + O_MTP);
  k_finalize<<<256, 256, 0, stream>>>(ws + O_DEG0, ws + O_DEG1, ws + O_CNTDR, ws + O_CNTPD,
                                      ws + O_MOR, ws + O_MTR, ws + O_MTD, ws + O_MTP,
                                      ws + O_DINV0, ws + O_DINV1, ws + O_RCDR, ws + O_RCOR,
                                      ws + O_RCTR, ws + O_RCPD, ws + O_RCTD, ws + O_RCTP);

  // transposes to flat layout (slice t < T1)
  k_transpose<<<dim3(NROOM / 64, T1, NB), 256, 0, stream>>>(x_room, ws + O_RF, NROOM);
  k_transpose<<<dim3(NDEV / 64, T1, NB), 256, 0, stream>>>(x_device, ws + O_DF, NDEV);

  // GLU conv1
  k_glu_conv1_prop<<<dim3(NPROP / 64, T1, NB), 256, 0, stream>>>(x_property, conv1_W, conv1_b,
                                                                 ws + O_PF);
  k_glu_conv_small1<<<dim3(T1, NB), 64, 0, stream>>>(x_outside, conv1_W + 128 * 192,
                                                     conv1_b + 128, ws + O_OF);
  k_glu_conv_small1<<<dim3(T1, NB), 64, 0, stream>>>(x_time, conv1_W + 2 * 128 * 192,
                                                     conv1_b + 2 * 128, ws + O_TF);

  // GCN h matrices, then edge scatters
  k_gcn_h<<<448, 256, 0, stream>>>(ws + O_RF, gcn_W, ws + O_H0, ws + O_H1);
  k_scatter_gcn<<<(E_hh * 224 + 255) / 256, 256, 0, stream>>>(hh_src, hh_dst, hh_w, E_hh,
                                                              ws + O_H0, ws + O_DINV0,
                                                              ws + O_ROOMG);
  k_scatter_gcn<<<(E_hv * 224 + 255) / 256, 256, 0, stream>>>(hv_src, hv_dst, hv_w, E_hv,
                                                              ws + O_H1, ws + O_DINV1,
                                                              ws + O_ROOMG);
  k_scatter_sage<<<(E_dr * 224 + 255) / 256, 256, 0, stream>>>(dr_src, dr_dst, E_dr, ws + O_DF,
                                                               ND, ws + O_AGGDR, NR);
  k_scatter_sage<<<(E_pd * 224 + 255) / 256, 256, 0, stream>>>(pd_src, pd_dst, E_pd, ws + O_PF,
                                                               NP, ws + O_AGGPD, ND);

  // node finals (in-place: roomg -> room_s, aggpd -> dev_s, pf -> prop_s)
  k_room_final<<<224, 256, 0, stream>>>(ws + O_RF, ws + O_H0, ws + O_H1, ws + O_AGGDR, ws + O_OF,
                                        ws + O_TF, ws + O_MOR, ws + O_MTR, ws + O_DINV0,
                                        ws + O_DINV1, ws + O_RCDR, ws + O_RCOR, ws + O_RCTR,
                                        sage_Wl, ws + O_WSR, ws + O_BSR, ws + O_ROOMG);
  k_dev_final<<<896, 256, 0, stream>>>(ws + O_AGGPD, ws + O_DF, ws + O_TF, ws + O_MTD,
                                       ws + O_RCPD, ws + O_RCTD, sage_Wl, ws + O_WSD, ws + O_BSD);
  k_prop_final<<<3584, 256, 0, stream>>>(ws + O_PF, ws + O_TF, ws + O_MTP, ws + O_RCTP,
                                         sage_Wl + 5 * 4096, sage_Wr + 5 * 4096,
                                         sage_bl + 5 * 64);

  // outputs: room/dev relu+LN from flat; prop/out/time GLU conv2 with fused LN
  k_ln_flat<NROOM><<<(NB * T2 * NROOM) / 256, 256, 0, stream>>>(ws + O_ROOMG, ln_g, ln_b,
                                                                out + OUT_ROOM);
  k_ln_flat<NDEV><<<(NB * T2 * NDEV) / 256, 256, 0, stream>>>(ws + O_AGGPD, ln_g + 64, ln_b + 64,
                                                              out + OUT_DEV);
  k_glu_conv2_prop<<<dim3(NPROP / 64, T2, NB), 256, 0, stream>>>(
      ws + O_PF, conv2_W, conv2_b, ln_g + 2 * 64, ln_b + 2 * 64, out + OUT_PROP);
  k_glu_conv_small2<<<dim3(T2, NB), 64, 0, stream>>>(ws + O_OF, conv2_W + 128 * 192,
                                                     conv2_b + 128, ln_g + 3 * 64, ln_b + 3 * 64,
                                                     out + OUT_OUT);
  k_glu_conv_small2<<<dim3(T2, NB), 64, 0, stream>>>(ws + O_TF, conv2_W + 2 * 128 * 192,
                                                     conv2_b + 2 * 128, ln_g + 4 * 64,
                                                     ln_b + 4 * 64, out + OUT_TIME);
}

// Round 2
// 4018.566 us; speedup vs baseline: 2.1091x; 2.1091x over previous
//
#include <hip/hip_runtime.h>
#include <math.h>

// ---------------- problem constants ----------------
#define T_IN  16
#define T1    14
#define T2    12
#define NB    16
#define NPROP 4096
#define NDEV  1024
#define NROOM 256
#define NR    4096    // B*N_ROOM
#define ND    16384   // B*N_DEV
#define NP    65536   // B*N_PROP
// B*N_OUT = B*N_TIME = 16

// ---------------- workspace layout (floats) ----------------
constexpr size_t SZ_PF = (size_t)T1 * NP * 64;   // 58,720,256
constexpr size_t SZ_DF = (size_t)T1 * ND * 64;   // 14,680,064
constexpr size_t SZ_RF = (size_t)T1 * NR * 64;   //  3,670,016
constexpr size_t SZ_OF = (size_t)T1 * 16 * 64;   //     14,336

constexpr size_t O_PF   = 0;
constexpr size_t O_DF   = O_PF + SZ_PF;
constexpr size_t O_RF   = O_DF + SZ_DF;
constexpr size_t O_H0   = O_RF + SZ_RF;
constexpr size_t O_H1   = O_H0 + SZ_RF;
constexpr size_t O_OF   = O_H1 + SZ_RF;
constexpr size_t O_TF   = O_OF + SZ_OF;
constexpr size_t O_WSR  = O_TF + SZ_OF;      // Wr0+Wr2+Wr3 (4096)
constexpr size_t O_WSD  = O_WSR + 4096;      // Wr1+Wr4     (4096)
constexpr size_t O_BSR  = O_WSD + 4096;      // summed room bias (64)
constexpr size_t O_BSD  = O_BSR + 64;        // summed dev bias  (64)
constexpr size_t O_DINV0= O_BSD + 64;
constexpr size_t O_DINV1= O_DINV0 + 4096;
constexpr size_t O_RCDR = O_DINV1 + 4096;
constexpr size_t O_RCOR = O_RCDR + 4096;
constexpr size_t O_RCTR = O_RCOR + 4096;
constexpr size_t O_RCPD = O_RCTR + 4096;
constexpr size_t O_RCTD = O_RCPD + 16384;
constexpr size_t O_RCTP = O_RCTD + 16384;
// bf16 conv weights, k-permuted (k' = kk*64 + i): [128][192] shorts each
constexpr size_t O_WB1  = O_RCTP + 65536;    // 24576 shorts = 12288 float slots
constexpr size_t O_WB2  = O_WB1 + 12288;
// ---- zero-initialized region starts here ----
constexpr size_t O_ZERO  = O_WB2 + 12288;
constexpr size_t O_ROOMG = O_ZERO;                    // gcn edge scatter acc / room_s (3,670,016)
constexpr size_t O_AGGDR = O_ROOMG + SZ_RF;           // sage dr agg                   (3,670,016)
constexpr size_t O_AGGPD = O_AGGDR + SZ_RF;           // sage pd agg / dev_s          (14,680,064)
constexpr size_t O_DEG0  = O_AGGPD + SZ_DF;
constexpr size_t O_DEG1  = O_DEG0 + 4096;
constexpr size_t O_CNTDR = O_DEG1 + 4096;
constexpr size_t O_CNTPD = O_CNTDR + 4096;
constexpr size_t O_MOR   = O_CNTPD + 16384;           // 4096 x 16
constexpr size_t O_MTR   = O_MOR + 65536;             // 4096 x 16
constexpr size_t O_MTD   = O_MTR + 65536;             // 16384 x 16
constexpr size_t O_MTP   = O_MTD + 262144;            // 65536 x 16
constexpr size_t O_END   = O_MTP + 1048576;
constexpr size_t ZERO_CNT = O_END - O_ZERO;

// output (floats) offsets in d_out (NCHW, concatenated in return order)
constexpr size_t OUT_ROOM = 0;
constexpr size_t OUT_DEV  = 3145728;
constexpr size_t OUT_PROP = 15728640;
constexpr size_t OUT_OUT  = 66060288;
constexpr size_t OUT_TIME = 66072576;

__device__ __forceinline__ float sigm(float x) { return 1.f / (1.f + __expf(-x)); }

__device__ __forceinline__ unsigned short f2bf(float f) {
  unsigned u = __float_as_uint(f);
  u += 0x7fffu + ((u >> 16) & 1u);
  return (unsigned short)(u >> 16);
}
__device__ __forceinline__ float bf2f(unsigned short h) {
  return __uint_as_float(((unsigned)h) << 16);
}

typedef __attribute__((ext_vector_type(8))) short bf16x8;
typedef __attribute__((ext_vector_type(4))) float floatx4;

__device__ __forceinline__ floatx4 mfma16(bf16x8 a, bf16x8 b, floatx4 c) {
  return __builtin_amdgcn_mfma_f32_16x16x32_bf16(a, b, c, 0, 0, 0);
}

// 64x64 matmul accumulate: acc[d] += sum_c x[c] * W[c*64+d]
__device__ __forceinline__ void mm64(float4 acc[16], const float x[64], const float* __restrict__ W) {
#pragma unroll
  for (int c = 0; c < 64; ++c) {
    const float a = x[c];
    const float4* Wr = (const float4*)(W + c * 64);
#pragma unroll
    for (int d = 0; d < 16; ++d) {
      const float4 w = Wr[d];
      acc[d].x += a * w.x; acc[d].y += a * w.y; acc[d].z += a * w.z; acc[d].w += a * w.w;
    }
  }
}

// ---------------- small prep kernels ----------------
__global__ void k_prep(const float* __restrict__ sWr, const float* __restrict__ gcnb,
                       const float* __restrict__ sbl, float* __restrict__ Wsr,
                       float* __restrict__ Wsd, float* __restrict__ bsr, float* __restrict__ bsd) {
  const int k = blockIdx.x * 256 + threadIdx.x;
  if (k < 4096) {
    Wsr[k] = sWr[k] + sWr[2 * 4096 + k] + sWr[3 * 4096 + k];
    Wsd[k] = sWr[4096 + k] + sWr[4 * 4096 + k];
  }
  if (k < 64) {
    bsr[k] = gcnb[k] + gcnb[64 + k] + sbl[k] + sbl[2 * 64 + k] + sbl[3 * 64 + k];
    bsd[k] = sbl[64 + k] + sbl[4 * 64 + k];
  }
}

// convert prop conv weights (conv index 0) to bf16 with k' = kk*64 + i ordering
__global__ void k_wbf(const float* __restrict__ W1, const float* __restrict__ W2,
                      unsigned short* __restrict__ wb1, unsigned short* __restrict__ wb2) {
  const int idx = blockIdx.x * 256 + threadIdx.x;
  if (idx >= 128 * 192) return;
  const int o = idx / 192, kp = idx % 192;
  const int kk = kp >> 6, i = kp & 63;
  const size_t srcoff = (size_t)o * 192 + i * 3 + kk;
  wb1[idx] = f2bf(W1[srcoff]);
  wb2[idx] = f2bf(W2[srcoff]);
}

__global__ void k_count_w(const int* __restrict__ dst, const float* __restrict__ w, int E,
                          float* __restrict__ deg) {
  const int e = blockIdx.x * 256 + threadIdx.x;
  if (e < E) atomicAdd(&deg[dst[e]], w[e]);
}
__global__ void k_count1(const int* __restrict__ dst, int E, float* __restrict__ cnt) {
  const int e = blockIdx.x * 256 + threadIdx.x;
  if (e < E) atomicAdd(&cnt[dst[e]], 1.f);
}
__global__ void k_cmat(const int* __restrict__ src, const int* __restrict__ dst, int E,
                       float* __restrict__ M) {
  const int e = blockIdx.x * 256 + threadIdx.x;
  if (e < E) atomicAdd(&M[(size_t)dst[e] * 16 + src[e]], 1.f);
}

__global__ void k_finalize(const float* __restrict__ deg0, const float* __restrict__ deg1,
                           const float* __restrict__ cntdr, const float* __restrict__ cntpd,
                           const float* __restrict__ MOR, const float* __restrict__ MTR,
                           const float* __restrict__ MTD, const float* __restrict__ MTP,
                           float* __restrict__ dinv0, float* __restrict__ dinv1,
                           float* __restrict__ rcdr, float* __restrict__ rcor,
                           float* __restrict__ rctr, float* __restrict__ rcpd,
                           float* __restrict__ rctd, float* __restrict__ rctp) {
  const int i = blockIdx.x * 256 + threadIdx.x;  // 65536 threads
  if (i < 4096) {
    dinv0[i] = rsqrtf(deg0[i] + 1.f);   // +1 = self-loop weight
    dinv1[i] = rsqrtf(deg1[i] + 1.f);
    rcdr[i] = 1.f / fmaxf(cntdr[i], 1.f);
    float s0 = 0.f, s1 = 0.f;
    for (int s = 0; s < 16; ++s) { s0 += MOR[i * 16 + s]; s1 += MTR[i * 16 + s]; }
    rcor[i] = 1.f / fmaxf(s0, 1.f);
    rctr[i] = 1.f / fmaxf(s1, 1.f);
  }
  if (i < 16384) {
    rcpd[i] = 1.f / fmaxf(cntpd[i], 1.f);
    float s = 0.f;
    for (int k = 0; k < 16; ++k) s += MTD[i * 16 + k];
    rctd[i] = 1.f / fmaxf(s, 1.f);
  }
  {
    float s = 0.f;
    for (int k = 0; k < 16; ++k) s += MTP[(size_t)i * 16 + k];
    rctp[i] = 1.f / fmaxf(s, 1.f);
  }
}

// ---------------- NCHW (T sliced to T1) -> flat (T, B*N, C) ----------------
__global__ __launch_bounds__(256) void k_transpose(const float* __restrict__ x,
                                                   float* __restrict__ xf, int N) {
  __shared__ float tile[64][65];
  const int lane = threadIdx.x & 63, wave = threadIdx.x >> 6;
  const int n0 = blockIdx.x * 64, t = blockIdx.y, b = blockIdx.z;
#pragma unroll
  for (int cc = wave; cc < 64; cc += 4)
    tile[cc][lane] = x[(((size_t)b * 64 + cc) * T_IN + t) * N + n0 + lane];
  __syncthreads();
  const size_t NN = (size_t)NB * N;
#pragma unroll
  for (int nn = wave; nn < 64; nn += 4)
    xf[((size_t)t * NN + (size_t)b * N + n0 + nn) * 64 + lane] = tile[lane][nn];
}

// ---------------- MFMA GLU conv1 on property: NCHW in -> flat pf out ----------------
// block: 128 pixels x 128 out-channels, K=192 (k' = kk*64 + i)
__global__ __launch_bounds__(256) void k_conv1_mfma(const float* __restrict__ x,
                                                    const unsigned short* __restrict__ Wb,
                                                    const float* __restrict__ bias,
                                                    float* __restrict__ pf) {
  __shared__ unsigned short xs[128][200];  // [pixel][k'], pitch 200 for banking
  const int lane = threadIdx.x & 63, wave = threadIdx.x >> 6;
  const int quad = lane >> 4, p = lane & 15;
  const int n0 = blockIdx.x * 128, t = blockIdx.y, b = blockIdx.z;
  // stage: row r' = kk*64+i, coalesced global read, transposed bf16 LDS write
  for (int rr = wave; rr < 192; rr += 4) {
    const int i = rr & 63, kk = rr >> 6;
    const float* src = x + (((size_t)b * 64 + i) * T_IN + (t + kk)) * NPROP + n0;
    xs[lane][rr] = f2bf(src[lane]);
    xs[64 + lane][rr] = f2bf(src[64 + lane]);
  }
  __syncthreads();
  floatx4 acc[8][2];
#pragma unroll
  for (int mt = 0; mt < 8; ++mt)
#pragma unroll
    for (int nt = 0; nt < 2; ++nt) acc[mt][nt] = (floatx4){0.f, 0.f, 0.f, 0.f};
#pragma unroll
  for (int k0 = 0; k0 < 192; k0 += 32) {
    const bf16x8 b0 = *(const bf16x8*)&xs[wave * 32 + p][k0 + quad * 8];
    const bf16x8 b1 = *(const bf16x8*)&xs[wave * 32 + 16 + p][k0 + quad * 8];
#pragma unroll
    for (int mt = 0; mt < 8; ++mt) {
      const bf16x8 a = *(const bf16x8*)(Wb + (size_t)(mt * 16 + p) * 192 + k0 + quad * 8);
      acc[mt][0] = mfma16(a, b0, acc[mt][0]);
      acc[mt][1] = mfma16(a, b1, acc[mt][1]);
    }
  }
  // epilogue: GLU, write flat pf
  const size_t pixbase = (size_t)t * NP + (size_t)b * NPROP + n0;
#pragma unroll
  for (int mt = 0; mt < 4; ++mt) {
    const int c0 = mt * 16 + quad * 4;
    const float4 pb = *(const float4*)(bias + c0);
    const float4 qb = *(const float4*)(bias + 64 + c0);
#pragma unroll
    for (int nt = 0; nt < 2; ++nt) {
      const int n = wave * 32 + nt * 16 + p;
      const unsigned short* xi = &xs[n][128 + c0];  // xin = tap kk=2 -> k' = 128 + c
      float4 o;
      o.x = (acc[mt][nt][0] + pb.x + bf2f(xi[0])) * sigm(acc[mt + 4][nt][0] + qb.x);
      o.y = (acc[mt][nt][1] + pb.y + bf2f(xi[1])) * sigm(acc[mt + 4][nt][1] + qb.y);
      o.z = (acc[mt][nt][2] + pb.z + bf2f(xi[2])) * sigm(acc[mt + 4][nt][2] + qb.z);
      o.w = (acc[mt][nt][3] + pb.w + bf2f(xi[3])) * sigm(acc[mt + 4][nt][3] + qb.w);
      *(float4*)(pf + (pixbase + n) * 64 + c0) = o;
    }
  }
}

// ---------------- MFMA GLU conv2 on prop: flat in (relu on read) -> fused LN -> NCHW ----------
__global__ __launch_bounds__(256) void k_conv2_mfma(const float* __restrict__ pf,
                                                    const unsigned short* __restrict__ Wb,
                                                    const float* __restrict__ bias,
                                                    const float* __restrict__ lg,
                                                    const float* __restrict__ lb,
                                                    float* __restrict__ out) {
  __shared__ unsigned short xs[128][200];
  const int lane = threadIdx.x & 63, wave = threadIdx.x >> 6;
  const int quad = lane >> 4, p = lane & 15;
  const int n0 = blockIdx.x * 128, t = blockIdx.y, b = blockIdx.z;
  // stage: float4 channel-contiguous reads, relu, 4x bf16 contiguous LDS write
  const int i4 = threadIdx.x & 15, pxb = threadIdx.x >> 4;
  for (int kk = 0; kk < 3; ++kk) {
    const float* srcbase =
        pf + ((size_t)(t + kk) * NP + (size_t)b * NPROP + n0) * 64 + i4 * 4;
#pragma unroll
    for (int h = 0; h < 8; ++h) {
      const int px = h * 16 + pxb;
      const float4 v = *(const float4*)(srcbase + (size_t)px * 64);
      const unsigned a0 =
          (unsigned)f2bf(fmaxf(v.x, 0.f)) | ((unsigned)f2bf(fmaxf(v.y, 0.f)) << 16);
      const unsigned a1 =
          (unsigned)f2bf(fmaxf(v.z, 0.f)) | ((unsigned)f2bf(fmaxf(v.w, 0.f)) << 16);
      *(uint2*)&xs[px][kk * 64 + i4 * 4] = make_uint2(a0, a1);
    }
  }
  __syncthreads();
  floatx4 acc[8][2];
#pragma unroll
  for (int mt = 0; mt < 8; ++mt)
#pragma unroll
    for (int nt = 0; nt < 2; ++nt) acc[mt][nt] = (floatx4){0.f, 0.f, 0.f, 0.f};
#pragma unroll
  for (int k0 = 0; k0 < 192; k0 += 32) {
    const bf16x8 b0 = *(const bf16x8*)&xs[wave * 32 + p][k0 + quad * 8];
    const bf16x8 b1 = *(const bf16x8*)&xs[wave * 32 + 16 + p][k0 + quad * 8];
#pragma unroll
    for (int mt = 0; mt < 8; ++mt) {
      const bf16x8 a = *(const bf16x8*)(Wb + (size_t)(mt * 16 + p) * 192 + k0 + quad * 8);
      acc[mt][0] = mfma16(a, b0, acc[mt][0]);
      acc[mt][1] = mfma16(a, b1, acc[mt][1]);
    }
  }
  // epilogue: GLU + per-pixel LayerNorm (cross-quad shuffle reduce) + NCHW store
  float o[4][2][4];
  float s1[2] = {0.f, 0.f}, s2[2] = {0.f, 0.f};
#pragma unroll
  for (int mt = 0; mt < 4; ++mt) {
    const int c0 = mt * 16 + quad * 4;
    const float4 pb = *(const float4*)(bias + c0);
    const float4 qb = *(const float4*)(bias + 64 + c0);
#pragma unroll
    for (int nt = 0; nt < 2; ++nt) {
      const int n = wave * 32 + nt * 16 + p;
      const unsigned short* xi = &xs[n][128 + c0];
      const float pbv[4] = {pb.x, pb.y, pb.z, pb.w};
      const float qbv[4] = {qb.x, qb.y, qb.z, qb.w};
#pragma unroll
      for (int r = 0; r < 4; ++r) {
        const float ov =
            (acc[mt][nt][r] + pbv[r] + bf2f(xi[r])) * sigm(acc[mt + 4][nt][r] + qbv[r]);
        o[mt][nt][r] = ov;
        s1[nt] += ov;
        s2[nt] += ov * ov;
      }
    }
  }
#pragma unroll
  for (int nt = 0; nt < 2; ++nt) {
    s1[nt] += __shfl_xor(s1[nt], 16);
    s1[nt] += __shfl_xor(s1[nt], 32);
    s2[nt] += __shfl_xor(s2[nt], 16);
    s2[nt] += __shfl_xor(s2[nt], 32);
  }
  float mean[2], rs[2];
#pragma unroll
  for (int nt = 0; nt < 2; ++nt) {
    mean[nt] = s1[nt] * (1.f / 64.f);
    const float var = s2[nt] * (1.f / 64.f) - mean[nt] * mean[nt];
    rs[nt] = rsqrtf(var + 1e-5f);
  }
#pragma unroll
  for (int mt = 0; mt < 4; ++mt) {
    const int c0 = mt * 16 + quad * 4;
    const float4 lgv = *(const float4*)(lg + c0);
    const float4 lbv = *(const float4*)(lb + c0);
    const float lgr[4] = {lgv.x, lgv.y, lgv.z, lgv.w};
    const float lbr[4] = {lbv.x, lbv.y, lbv.z, lbv.w};
#pragma unroll
    for (int nt = 0; nt < 2; ++nt) {
      const int n = wave * 32 + nt * 16 + p;
#pragma unroll
      for (int r = 0; r < 4; ++r) {
        const int c = c0 + r;
        out[(((size_t)b * 64 + c) * T2 + t) * NPROP + n0 + n] =
            (o[mt][nt][r] - mean[nt]) * rs[nt] * lgr[r] + lbr[r];
      }
    }
  }
}

// ---------------- GLU conv, N==1 tensors ----------------
__global__ __launch_bounds__(64) void k_glu_conv_small1(const float* __restrict__ x,
                                                        const float* __restrict__ W,
                                                        const float* __restrict__ bias,
                                                        float* __restrict__ xfout) {
  __shared__ float xl[192];
  const int c = threadIdx.x;
  const int t = blockIdx.x, b = blockIdx.y;
  for (int r = c; r < 192; r += 64) {
    const int i = r / 3, k = r - (r / 3) * 3;
    xl[r] = x[((size_t)b * 64 + i) * T_IN + (t + k)];
  }
  __syncthreads();
  float p = 0.f, q = 0.f;
  for (int r0 = 0; r0 < 192; r0 += 4) {
    const float4 xv = *(const float4*)(xl + r0);
    const float4 wp = *(const float4*)(W + (size_t)c * 192 + r0);
    const float4 wq = *(const float4*)(W + (size_t)(c + 64) * 192 + r0);
    p += wp.x * xv.x + wp.y * xv.y + wp.z * xv.z + wp.w * xv.w;
    q += wq.x * xv.x + wq.y * xv.y + wq.z * xv.z + wq.w * xv.w;
  }
  const float xin = xl[c * 3 + 2];
  xfout[((size_t)t * 16 + b) * 64 + c] = (p + bias[c] + xin) * sigm(q + bias[c + 64]);
}

__global__ __launch_bounds__(64) void k_glu_conv_small2(const float* __restrict__ xfin,
                                                        const float* __restrict__ W,
                                                        const float* __restrict__ bias,
                                                        const float* __restrict__ lg,
                                                        const float* __restrict__ lb,
                                                        float* __restrict__ out) {
  __shared__ float xl[192];
  const int c = threadIdx.x;
  const int t = blockIdx.x, b = blockIdx.y;
  for (int r = c; r < 192; r += 64) {
    const int i = r / 3, k = r - (r / 3) * 3;
    xl[r] = fmaxf(xfin[((size_t)(t + k) * 16 + b) * 64 + i], 0.f);
  }
  __syncthreads();
  float p = 0.f, q = 0.f;
  for (int r0 = 0; r0 < 192; r0 += 4) {
    const float4 xv = *(const float4*)(xl + r0);
    const float4 wp = *(const float4*)(W + (size_t)c * 192 + r0);
    const float4 wq = *(const float4*)(W + (size_t)(c + 64) * 192 + r0);
    p += wp.x * xv.x + wp.y * xv.y + wp.z * xv.z + wp.w * xv.w;
    q += wq.x * xv.x + wq.y * xv.y + wq.z * xv.z + wq.w * xv.w;
  }
  const float xin = xl[c * 3 + 2];
  const float o = (p + bias[c] + xin) * sigm(q + bias[c + 64]);
  float s1 = o, s2 = o * o;
#pragma unroll
  for (int off = 32; off > 0; off >>= 1) {
    s1 += __shfl_xor(s1, off);
    s2 += __shfl_xor(s2, off);
  }
  const float m = s1 * (1.f / 64.f);
  const float var = s2 * (1.f / 64.f) - m * m;
  out[((size_t)b * 64 + c) * T2 + t] = (o - m) * rsqrtf(var + 1e-5f) * lg[c] + lb[c];
}

// ---------------- h = rf @ gcn_W[g], g in {0,1} ----------------
__global__ __launch_bounds__(256) void k_gcn_h(const float* __restrict__ rf,
                                               const float* __restrict__ gcnW,
                                               float* __restrict__ h0, float* __restrict__ h1) {
  const int idx = blockIdx.x * 256 + threadIdx.x;
  const int i = idx & 4095;
  const int tg = idx >> 12;
  const int t = tg % 14;
  const int g = tg / 14;
  if (g >= 2) return;
  const size_t row = ((size_t)t * NR + i) * 64;
  float x[64];
  const float4* xr = (const float4*)(rf + row);
#pragma unroll
  for (int c4 = 0; c4 < 16; ++c4) {
    const float4 v = xr[c4];
    x[c4 * 4] = v.x; x[c4 * 4 + 1] = v.y; x[c4 * 4 + 2] = v.z; x[c4 * 4 + 3] = v.w;
  }
  float4 acc[16];
#pragma unroll
  for (int d = 0; d < 16; ++d) acc[d] = make_float4(0.f, 0.f, 0.f, 0.f);
  mm64(acc, x, gcnW + (size_t)g * 4096);
  float4* po = (float4*)((g ? h1 : h0) + row);
#pragma unroll
  for (int d = 0; d < 16; ++d) po[d] = acc[d];
}

// ---------------- edge scatters (atomics) ----------------
__global__ __launch_bounds__(256) void k_scatter_gcn(const int* __restrict__ src,
                                                     const int* __restrict__ dst,
                                                     const float* __restrict__ w, int E,
                                                     const float* __restrict__ h,
                                                     const float* __restrict__ dinv,
                                                     float* __restrict__ outacc) {
  const int gid = blockIdx.x * 256 + threadIdx.x;
  if (gid >= E * 224) return;
  const int cq = gid & 15;
  const int t = (gid >> 4) % 14;
  const int e = gid / 224;
  const int s = src[e], d = dst[e];
  const float nrm = dinv[s] * w[e] * dinv[d];
  const float4 hv = *(const float4*)(h + ((size_t)t * NR + s) * 64 + cq * 4);
  float* o = outacc + ((size_t)t * NR + d) * 64 + cq * 4;
  atomicAdd(o + 0, hv.x * nrm);
  atomicAdd(o + 1, hv.y * nrm);
  atomicAdd(o + 2, hv.z * nrm);
  atomicAdd(o + 3, hv.w * nrm);
}

__global__ __launch_bounds__(256) void k_scatter_sage(const int* __restrict__ src,
                                                      const int* __restrict__ dst, int E,
                                                      const float* __restrict__ xsrc, int NNsrc,
                                                      float* __restrict__ agg, int NNdst) {
  const int gid = blockIdx.x * 256 + threadIdx.x;
  if (gid >= E * 224) return;
  const int cq = gid & 15;
  const int t = (gid >> 4) % 14;
  const int e = gid / 224;
  const int s = src[e], d = dst[e];
  const float4 v = *(const float4*)(xsrc + ((size_t)t * NNsrc + s) * 64 + cq * 4);
  float* o = agg + ((size_t)t * NNdst + d) * 64 + cq * 4;
  atomicAdd(o + 0, v.x);
  atomicAdd(o + 1, v.y);
  atomicAdd(o + 2, v.z);
  atomicAdd(o + 3, v.w);
}

// ---------------- node "final" kernels ----------------
__global__ __launch_bounds__(256) void k_room_final(
    const float* __restrict__ rf, const float* __restrict__ h0, const float* __restrict__ h1,
    const float* __restrict__ aggdr, const float* __restrict__ of, const float* __restrict__ tf,
    const float* __restrict__ MOR, const float* __restrict__ MTR, const float* __restrict__ dinv0,
    const float* __restrict__ dinv1, const float* __restrict__ rcdr,
    const float* __restrict__ rcor, const float* __restrict__ rctr, const float* __restrict__ Wl,
    const float* __restrict__ Wsr, const float* __restrict__ bsr, float* __restrict__ roomg) {
  const int idx = blockIdx.x * 256 + threadIdx.x;
  const int i = idx & 4095;
  const int t = idx >> 12;
  if (t >= 14) return;
  const size_t row = ((size_t)t * NR + i) * 64;
  const float d0 = dinv0[i], d1 = dinv1[i];
  const float d0sq = d0 * d0, d1sq = d1 * d1;
  float4 acc[16];
  {
    const float4* pg = (const float4*)(roomg + row);
    const float4* p0 = (const float4*)(h0 + row);
    const float4* p1 = (const float4*)(h1 + row);
    const float4* pb = (const float4*)bsr;
#pragma unroll
    for (int d = 0; d < 16; ++d) {
      float4 a = pg[d];
      const float4 v0 = p0[d], v1 = p1[d], bb = pb[d];
      a.x += bb.x + v0.x * d0sq + v1.x * d1sq;
      a.y += bb.y + v0.y * d0sq + v1.y * d1sq;
      a.z += bb.z + v0.z * d0sq + v1.z * d1sq;
      a.w += bb.w + v0.w * d0sq + v1.w * d1sq;
      acc[d] = a;
    }
  }
  float x[64];
  {
    const float rc = rcdr[i];
    const float4* pa = (const float4*)(aggdr + row);
#pragma unroll
    for (int c4 = 0; c4 < 16; ++c4) {
      const float4 v = pa[c4];
      x[c4 * 4] = v.x * rc; x[c4 * 4 + 1] = v.y * rc; x[c4 * 4 + 2] = v.z * rc; x[c4 * 4 + 3] = v.w * rc;
    }
  }
  mm64(acc, x, Wl);  // Wl0
  {
#pragma unroll
    for (int c = 0; c < 64; ++c) x[c] = 0.f;
    for (int s = 0; s < 16; ++s) {
      const float ms = MOR[i * 16 + s];
      const float4* pr = (const float4*)(of + ((size_t)t * 16 + s) * 64);
#pragma unroll
      for (int c4 = 0; c4 < 16; ++c4) {
        const float4 v = pr[c4];
        x[c4 * 4] += ms * v.x; x[c4 * 4 + 1] += ms * v.y; x[c4 * 4 + 2] += ms * v.z; x[c4 * 4 + 3] += ms * v.w;
      }
    }
    const float rc = rcor[i];
#pragma unroll
    for (int c = 0; c < 64; ++c) x[c] *= rc;
  }
  mm64(acc, x, Wl + 2 * 4096);  // Wl2
  {
#pragma unroll
    for (int c = 0; c < 64; ++c) x[c] = 0.f;
    for (int s = 0; s < 16; ++s) {
      const float ms = MTR[i * 16 + s];
      const float4* pr = (const float4*)(tf + ((size_t)t * 16 + s) * 64);
#pragma unroll
      for (int c4 = 0; c4 < 16; ++c4) {
        const float4 v = pr[c4];
        x[c4 * 4] += ms * v.x; x[c4 * 4 + 1] += ms * v.y; x[c4 * 4 + 2] += ms * v.z; x[c4 * 4 + 3] += ms * v.w;
      }
    }
    const float rc = rctr[i];
#pragma unroll
    for (int c = 0; c < 64; ++c) x[c] *= rc;
  }
  mm64(acc, x, Wl + 3 * 4096);  // Wl3
  {
    const float4* pr = (const float4*)(rf + row);
#pragma unroll
    for (int c4 = 0; c4 < 16; ++c4) {
      const float4 v = pr[c4];
      x[c4 * 4] = v.x; x[c4 * 4 + 1] = v.y; x[c4 * 4 + 2] = v.z; x[c4 * 4 + 3] = v.w;
    }
  }
  mm64(acc, x, Wsr);
  float4* po = (float4*)(roomg + row);
#pragma unroll
  for (int d = 0; d < 16; ++d) po[d] = acc[d];
}

__global__ __launch_bounds__(256) void k_dev_final(float* __restrict__ aggpd,
                                                   const float* __restrict__ df,
                                                   const float* __restrict__ tf,
                                                   const float* __restrict__ MTD,
                                                   const float* __restrict__ rcpd,
                                                   const float* __restrict__ rctd,
                                                   const float* __restrict__ Wl,
                                                   const float* __restrict__ Wsd,
                                                   const float* __restrict__ bsd) {
  const int idx = blockIdx.x * 256 + threadIdx.x;
  const int i = idx & 16383;
  const int t = idx >> 14;
  if (t >= 14) return;
  const size_t row = ((size_t)t * ND + i) * 64;
  float4 acc[16];
  const float4* pb = (const float4*)bsd;
#pragma unroll
  for (int d = 0; d < 16; ++d) acc[d] = pb[d];
  float x[64];
  {
    const float rc = rcpd[i];
    const float4* pa = (const float4*)(aggpd + row);
#pragma unroll
    for (int c4 = 0; c4 < 16; ++c4) {
      const float4 v = pa[c4];
      x[c4 * 4] = v.x * rc; x[c4 * 4 + 1] = v.y * rc; x[c4 * 4 + 2] = v.z * rc; x[c4 * 4 + 3] = v.w * rc;
    }
  }
  mm64(acc, x, Wl + 1 * 4096);  // Wl1
  {
#pragma unroll
    for (int c = 0; c < 64; ++c) x[c] = 0.f;
    for (int s = 0; s < 16; ++s) {
      const float ms = MTD[(size_t)i * 16 + s];
      const float4* pr = (const float4*)(tf + ((size_t)t * 16 + s) * 64);
#pragma unroll
      for (int c4 = 0; c4 < 16; ++c4) {
        const float4 v = pr[c4];
        x[c4 * 4] += ms * v.x; x[c4 * 4 + 1] += ms * v.y; x[c4 * 4 + 2] += ms * v.z; x[c4 * 4 + 3] += ms * v.w;
      }
    }
    const float rc = rctd[i];
#pragma unroll
    for (int c = 0; c < 64; ++c) x[c] *= rc;
  }
  mm64(acc, x, Wl + 4 * 4096);  // Wl4
  {
    const float4* pr = (const float4*)(df + row);
#pragma unroll
    for (int c4 = 0; c4 < 16; ++c4) {
      const float4 v = pr[c4];
      x[c4 * 4] = v.x; x[c4 * 4 + 1] = v.y; x[c4 * 4 + 2] = v.z; x[c4 * 4 + 3] = v.w;
    }
  }
  mm64(acc, x, Wsd);
  float4* po = (float4*)(aggpd + row);
#pragma unroll
  for (int d = 0; d < 16; ++d) po[d] = acc[d];
}

__global__ __launch_bounds__(256) void k_prop_final(float* __restrict__ pf,
                                                    const float* __restrict__ tf,
                                                    const float* __restrict__ MTP,
                                                    const float* __restrict__ rctp,
                                                    const float* __restrict__ Wl5,
                                                    const float* __restrict__ Wr5,
                                                    const float* __restrict__ bl5) {
  const int idx = blockIdx.x * 256 + threadIdx.x;
  const int i = idx & 65535;
  const int t = idx >> 16;
  if (t >= 14) return;
  const size_t row = ((size_t)t * NP + i) * 64;
  float4 acc[16];
  const float4* pb = (const float4*)bl5;
#pragma unroll
  for (int d = 0; d < 16; ++d) acc[d] = pb[d];
  float x[64];
  {
#pragma unroll
    for (int c = 0; c < 64; ++c) x[c] = 0.f;
    for (int s = 0; s < 16; ++s) {
      const float ms = MTP[(size_t)i * 16 + s];
      const float4* pr = (const float4*)(tf + ((size_t)t * 16 + s) * 64);
#pragma unroll
      for (int c4 = 0; c4 < 16; ++c4) {
        const float4 v = pr[c4];
        x[c4 * 4] += ms * v.x; x[c4 * 4 + 1] += ms * v.y; x[c4 * 4 + 2] += ms * v.z; x[c4 * 4 + 3] += ms * v.w;
      }
    }
    const float rc = rctp[i];
#pragma unroll
    for (int c = 0; c < 64; ++c) x[c] *= rc;
  }
  mm64(acc, x, Wl5);
  {
    const float4* pr = (const float4*)(pf + row);
#pragma unroll
    for (int c4 = 0; c4 < 16; ++c4) {
      const float4 v = pr[c4];
      x[c4 * 4] = v.x; x[c4 * 4 + 1] = v.y; x[c4 * 4 + 2] = v.z; x[c4 * 4 + 3] = v.w;
    }
  }
  mm64(acc, x, Wr5);
  float4* po = (float4*)(pf + row);
#pragma unroll
  for (int d = 0; d < 16; ++d) po[d] = acc[d];
}

// ---------------- relu + layernorm over C + flat -> NCHW, for room/dev ----------------
template <int N>
__global__ __launch_bounds__(256) void k_ln_flat(const float* __restrict__ xf,
                                                 const float* __restrict__ lg,
                                                 const float* __restrict__ lb,
                                                 float* __restrict__ out) {
  const int idx = blockIdx.x * 256 + threadIdx.x;
  const int n = idx % N;
  const int t = (idx / N) % T2;
  const int b = idx / (N * T2);
  if (b >= NB) return;
  const float4* pr = (const float4*)(xf + ((size_t)t * (NB * N) + (size_t)b * N + n) * 64);
  float v[64];
  float s1 = 0.f, s2 = 0.f;
#pragma unroll
  for (int c4 = 0; c4 < 16; ++c4) {
    float4 a = pr[c4];
    a.x = fmaxf(a.x, 0.f); a.y = fmaxf(a.y, 0.f); a.z = fmaxf(a.z, 0.f); a.w = fmaxf(a.w, 0.f);
    v[c4 * 4] = a.x; v[c4 * 4 + 1] = a.y; v[c4 * 4 + 2] = a.z; v[c4 * 4 + 3] = a.w;
    s1 += a.x + a.y + a.z + a.w;
    s2 += a.x * a.x + a.y * a.y + a.z * a.z + a.w * a.w;
  }
  const float m = s1 * (1.f / 64.f);
  const float var = s2 * (1.f / 64.f) - m * m;
  const float rs = rsqrtf(var + 1e-5f);
#pragma unroll
  for (int c = 0; c < 64; ++c)
    out[(((size_t)b * 64 + c) * T2 + t) * N + n] = (v[c] - m) * rs * lg[c] + lb[c];
}

// ---------------- host launcher ----------------
extern "C" void kernel_launch(void* const* d_in, const int* in_sizes, int n_in, void* d_out,
                              int out_size, void* d_ws, size_t ws_size, hipStream_t stream) {
  (void)n_in; (void)out_size; (void)ws_size;
  const float* x_room = (const float*)d_in[0];
  const float* x_device = (const float*)d_in[1];
  const float* x_property = (const float*)d_in[2];
  const float* x_outside = (const float*)d_in[3];
  const float* x_time = (const float*)d_in[4];
  const float* conv1_W = (const float*)d_in[5];
  const float* conv1_b = (const float*)d_in[6];
  const float* conv2_W = (const float*)d_in[7];
  const float* conv2_b = (const float*)d_in[8];
  const float* gcn_W = (const float*)d_in[9];
  const float* gcn_b = (const float*)d_in[10];
  const float* sage_Wl = (const float*)d_in[11];
  const float* sage_bl = (const float*)d_in[12];
  const float* sage_Wr = (const float*)d_in[13];
  const float* ln_g = (const float*)d_in[14];
  const float* ln_b = (const float*)d_in[15];
  const float* hh_w = (const float*)d_in[16];
  const float* hv_w = (const float*)d_in[17];
  const int* hh_src = (const int*)d_in[18];
  const int* hh_dst = (const int*)d_in[19];
  const int* hv_src = (const int*)d_in[20];
  const int* hv_dst = (const int*)d_in[21];
  const int* dr_src = (const int*)d_in[22];
  const int* dr_dst = (const int*)d_in[23];
  const int* pd_src = (const int*)d_in[24];
  const int* pd_dst = (const int*)d_in[25];
  const int* or_src = (const int*)d_in[26];
  const int* or_dst = (const int*)d_in[27];
  const int* tr_src = (const int*)d_in[28];
  const int* tr_dst = (const int*)d_in[29];
  const int* td_src = (const int*)d_in[30];
  const int* td_dst = (const int*)d_in[31];
  const int* tp_src = (const int*)d_in[32];
  const int* tp_dst = (const int*)d_in[33];
  const int E_hh = in_sizes[18], E_hv = in_sizes[20], E_dr = in_sizes[22], E_pd = in_sizes[24];
  const int E_or = in_sizes[26], E_tr = in_sizes[28], E_td = in_sizes[30], E_tp = in_sizes[32];

  float* ws = (float*)d_ws;
  float* out = (float*)d_out;
  unsigned short* wb1 = (unsigned short*)(ws + O_WB1);
  unsigned short* wb2 = (unsigned short*)(ws + O_WB2);

  hipMemsetAsync(ws + O_ZERO, 0, ZERO_CNT * sizeof(float), stream);

  k_prep<<<16, 256, 0, stream>>>(sage_Wr, gcn_b, sage_bl, ws + O_WSR, ws + O_WSD, ws + O_BSR,
                                 ws + O_BSD);
  k_wbf<<<96, 256, 0, stream>>>(conv1_W, conv2_W, wb1, wb2);

  k_count_w<<<(E_hh + 255) / 256, 256, 0, stream>>>(hh_dst, hh_w, E_hh, ws + O_DEG0);
  k_count_w<<<(E_hv + 255) / 256, 256, 0, stream>>>(hv_dst, hv_w, E_hv, ws + O_DEG1);
  k_count1<<<(E_dr + 255) / 256, 256, 0, stream>>>(dr_dst, E_dr, ws + O_CNTDR);
  k_count1<<<(E_pd + 255) / 256, 256, 0, stream>>>(pd_dst, E_pd, ws + O_CNTPD);
  k_cmat<<<(E_or + 255) / 256, 256, 0, stream>>>(or_src, or_dst, E_or, ws + O_MOR);
  k_cmat<<<(E_tr + 255) / 256, 256, 0, stream>>>(tr_src, tr_dst, E_tr, ws + O_MTR);
  k_cmat<<<(E_td + 255) / 256, 256, 0, stream>>>(td_src, td_dst, E_td, ws + O_MTD);
  k_cmat<<<(E_tp + 255) / 256, 256, 0, stream>>>(tp_src, tp_dst, E_tp, ws + O_MTP);
  k_finalize<<<256, 256, 0, stream>>>(ws + O_DEG0, ws + O_DEG1, ws + O_CNTDR, ws + O_CNTPD,
                                      ws + O_MOR, ws + O_MTR, ws + O_MTD, ws + O_MTP,
                                      ws + O_DINV0, ws + O_DINV1, ws + O_RCDR, ws + O_RCOR,
                                      ws + O_RCTR, ws + O_RCPD, ws + O_RCTD, ws + O_RCTP);

  k_transpose<<<dim3(NROOM / 64, T1, NB), 256, 0, stream>>>(x_room, ws + O_RF, NROOM);
  k_transpose<<<dim3(NDEV / 64, T1, NB), 256, 0, stream>>>(x_device, ws + O_DF, NDEV);

  // GLU conv1 (MFMA for prop, scalar for N==1 tensors)
  k_conv1_mfma<<<dim3(NPROP / 128, T1, NB), 256, 0, stream>>>(x_property, wb1, conv1_b,
                                                              ws + O_PF);
  k_glu_conv_small1<<<dim3(T1, NB), 64, 0, stream>>>(x_outside, conv1_W + 128 * 192,
                                                     conv1_b + 128, ws + O_OF);
  k_glu_conv_small1<<<dim3(T1, NB), 64, 0, stream>>>(x_time, conv1_W + 2 * 128 * 192,
                                                     conv1_b + 2 * 128, ws + O_TF);

  k_gcn_h<<<448, 256, 0, stream>>>(ws + O_RF, gcn_W, ws + O_H0, ws + O_H1);
  k_scatter_gcn<<<(E_hh * 224 + 255) / 256, 256, 0, stream>>>(hh_src, hh_dst, hh_w, E_hh,
                                                              ws + O_H0, ws + O_DINV0,
                                                              ws + O_ROOMG);
  k_scatter_gcn<<<(E_hv * 224 + 255) / 256, 256, 0, stream>>>(hv_src, hv_dst, hv_w, E_hv,
                                                              ws + O_H1, ws + O_DINV1,
                                                              ws + O_ROOMG);
  k_scatter_sage<<<(E_dr * 224 + 255) / 256, 256, 0, stream>>>(dr_src, dr_dst, E_dr, ws + O_DF,
                                                               ND, ws + O_AGGDR, NR);
  k_scatter_sage<<<(E_pd * 224 + 255) / 256, 256, 0, stream>>>(pd_src, pd_dst, E_pd, ws + O_PF,
                                                               NP, ws + O_AGGPD, ND);

  k_room_final<<<224, 256, 0, stream>>>(ws + O_RF, ws + O_H0, ws + O_H1, ws + O_AGGDR, ws + O_OF,
                                        ws + O_TF, ws + O_MOR, ws + O_MTR, ws + O_DINV0,
                                        ws + O_DINV1, ws + O_RCDR, ws + O_RCOR, ws + O_RCTR,
                                        sage_Wl, ws + O_WSR, ws + O_BSR, ws + O_ROOMG);
  k_dev_final<<<896, 256, 0, stream>>>(ws + O_AGGPD, ws + O_DF, ws + O_TF, ws + O_MTD,
                                       ws + O_RCPD, ws + O_RCTD, sage_Wl, ws + O_WSD, ws + O_BSD);
  k_prop_final<<<3584, 256, 0, stream>>>(ws + O_PF, ws + O_TF, ws + O_MTP, ws + O_RCTP,
                                         sage_Wl + 5 * 4096, sage_Wr + 5 * 4096,
                                         sage_bl + 5 * 64);

  k_ln_flat<NROOM><<<(NB * T2 * NROOM) / 256, 256, 0, stream>>>(ws + O_ROOMG, ln_g, ln_b,
                                                                out + OUT_ROOM);
  k_ln_flat<NDEV><<<(NB * T2 * NDEV) / 256, 256, 0, stream>>>(ws + O_AGGPD, ln_g + 64, ln_b + 64,
                                                              out + OUT_DEV);
  k_conv2_mfma<<<dim3(NPROP / 128, T2, NB), 256, 0, stream>>>(
      ws + O_PF, wb2, conv2_b, ln_g + 2 * 64, ln_b + 2 * 64, out + OUT_PROP);
  k_glu_conv_small2<<<dim3(T2, NB), 64, 0, stream>>>(ws + O_OF, conv2_W + 128 * 192,
                                                     conv2_b + 128, ln_g + 3 * 64, ln_b + 3 * 64,
                                                     out + OUT_OUT);
  k_glu_conv_small2<<<dim3(T2, NB), 64, 0, stream>>>(ws + O_TF, conv2_W + 2 * 128 * 192,
                                                     conv2_b + 2 * 128, ln_g + 4 * 64,
                                                     ln_b + 4 * 64, out + OUT_TIME);
}